// Round 17
// baseline (287.039 us; speedup 1.0000x reference)
//
#include <hip/hip_runtime.h>
#include <hip/hip_bf16.h>

#define B_ 128
#define S_ 196
#define E_ 768
#define M_ 768
#define KTOT (S_*E_)            // 150528
#define BK 256                  // k per superstep
#define SS_TOTAL (KTOT/BK)      // 588
#define KSPLIT 42
#define SSN (SS_TOTAL/KSPLIT)   // 14 exactly -- no straggle
#define ZC 6                    // z-chunks in reduce (42 = 6*7)

typedef __bf16 bf16x8 __attribute__((ext_vector_type(8)));
typedef __bf16 bf16x4 __attribute__((ext_vector_type(4)));
typedef float  f32x4  __attribute__((ext_vector_type(4)));

__device__ inline bf16x8 cvt8(const float* __restrict__ p) {
    float4 a = *(const float4*)p;
    float4 b = *(const float4*)(p + 4);
    bf16x8 r;
    r[0] = (__bf16)a.x; r[1] = (__bf16)a.y; r[2] = (__bf16)a.z; r[3] = (__bf16)a.w;
    r[4] = (__bf16)b.x; r[5] = (__bf16)b.y; r[6] = (__bf16)b.z; r[7] = (__bf16)b.w;
    return r;
}

// ---------------- prep: init_out | event_pool | pack_a (unchanged R14) -------
__global__ void prep(const float* __restrict__ mlp_b,
                     const float* __restrict__ fk_b,
                     const float* __restrict__ A,
                     const int* __restrict__ BE, int be_stride,
                     float* __restrict__ out,
                     float* __restrict__ EP,
                     __bf16* __restrict__ Apk) {
    const int bid = blockIdx.x;
    if (bid < 384) {
        int i = bid * 256 + threadIdx.x;
        int m = i % M_;
        out[i] = 0.9f * mlp_b[m] + 0.1f * fk_b[m];
    } else if (bid < 512) {
        int b = bid - 384;
        int s1 = BE[(b*4 + 0) * be_stride];
        int e1 = BE[(b*4 + 1) * be_stride];
        int s2 = BE[(b*4 + 2) * be_stride];
        int e2 = BE[(b*4 + 3) * be_stride];
        float inv1 = 1.0f / (float)(e1 - s1);
        float inv2 = 1.0f / (float)(e2 - s2);
        for (int c = threadIdx.x; c < E_; c += 256) {
            float sum1 = 0.f, sum2 = 0.f;
            for (int s = s1; s < e1; ++s) sum1 += A[((size_t)b * S_ + s) * E_ + c];
            for (int s = s2; s < e2; ++s) sum2 += A[((size_t)b * S_ + s) * E_ + c];
            EP[b * (2*E_) + c]       = sum1 * inv1;
            EP[b * (2*E_) + E_ + c]  = sum2 * inv2;
        }
    } else {
        const int nchunk = SS_TOTAL * 8 * 8 * 64;   // 2,408,448
        for (int c = (bid - 512) * 256 + threadIdx.x; c < nchunk; c += 3072 * 256) {
            int lane = c & 63;
            int kf   = (c >> 6) & 7;
            int bt   = (c >> 9) & 7;
            int ss   = c >> 12;
            int b = bt * 16 + (lane & 15);
            int k = ss * BK + kf * 32 + (lane >> 4) * 8;
            *(bf16x8*)(Apk + (size_t)c * 8) = cvt8(A + (size_t)b * KTOT + k);
        }
    }
}

// ---------------- fk_gemm: BARRIER-FREE, wave-private ----------------------
// Each wave owns 128b x 32m x (14 ss of 256k). It stages its own 32 W-rows
// per ss (1 row per float4 wave-load, fully coalesced; f32->bf16 on write)
// into a PRIVATE 16 KB LDS region (XOR swizzle (r&7)<<4 -> 2-way reads) and
// never synchronizes: no __syncthreads anywhere. W-chunk rotation (4 named
// 4-row sets, issued pre-compute) + A ping-pong give pure intra-wave
// pipelining. 504 wgs x 128 thr, 32 KB LDS/wg -> 4 wg/CU = 8 independent
// waves/CU (the harness-fill regime that measures 6.7 TB/s).

#define S_CHK(WR, j, sl)                                                      \
    _Pragma("unroll")                                                         \
    for (int i = 0; i < 4; ++i)                                               \
        WR[i] = *(const float4*)(wrow + (size_t)(4*(j)+i) * KTOT              \
                                      + (size_t)(sl) * BK);

#define W_CHK(WR, j)                                                          \
    _Pragma("unroll")                                                         \
    for (int i = 0; i < 4; ++i) {                                             \
        const int r = 4*(j)+i;                                                \
        bf16x4 h;                                                             \
        h[0] = (__bf16)WR[i].x; h[1] = (__bf16)WR[i].y;                       \
        h[2] = (__bf16)WR[i].z; h[3] = (__bf16)WR[i].w;                       \
        *(bf16x4*)(lds + r * 512 + ((lane * 8) ^ ((r & 7) << 4))) = h;        \
    }

#define LOAD_A(AREG, sl, kf)                                                  \
    _Pragma("unroll")                                                         \
    for (int bt = 0; bt < 8; ++bt)                                            \
        AREG[bt] = *(const bf16x8*)(abase +                                   \
            (((size_t)(ss0 + (sl)) * 8 + bt) * 8 + (kf)) * 512);

#define CALC(AREG, kf)                                                        \
    {                                                                         \
        bf16x8 wf0 = *(const bf16x8*)(lds + (r16) * 512 +                     \
                     (((kf) * 64 + kg * 16) ^ swz));                          \
        bf16x8 wf1 = *(const bf16x8*)(lds + (16 + r16) * 512 +                \
                     (((kf) * 64 + kg * 16) ^ swz));                          \
        _Pragma("unroll")                                                     \
        for (int bt = 0; bt < 8; ++bt) {                                      \
            acc[bt*2]   = __builtin_amdgcn_mfma_f32_16x16x32_bf16(AREG[bt],   \
                              wf0, acc[bt*2],   0, 0, 0);                     \
            acc[bt*2+1] = __builtin_amdgcn_mfma_f32_16x16x32_bf16(AREG[bt],   \
                              wf1, acc[bt*2+1], 0, 0, 0);                     \
        }                                                                     \
    }

__global__ __launch_bounds__(128, 2) void fk_gemm(const __bf16* __restrict__ Apk,
                                                  const float* __restrict__ W,
                                                  float* __restrict__ partial) {
    __shared__ __align__(16) char Wlds[2][32 * 512];    // per-wave private 16 KB

    const int wgid = blockIdx.x;                 // 0..503
    const int w    = (wgid & 7) * 63 + (wgid >> 3);  // XCD-chunked decode
    const int kz   = w / 12;                     // 0..41
    const int mtg  = w % 12;                     // 0..11
    const int wv   = threadIdx.x >> 6;           // 0..1
    const int lane = threadIdx.x & 63;
    const int r16  = lane & 15;
    const int kg   = lane >> 4;
    const int swz  = (r16 & 7) << 4;
    const int mt32 = mtg * 2 + wv;               // 0..23: m-rows [mt32*32, +32)
    const int ss0  = kz * SSN;

    char* lds = &Wlds[wv][0];

    const float* wrow = W + (size_t)(mt32 * 32) * KTOT
                          + (size_t)ss0 * BK + lane * 4;
    const __bf16* abase = Apk + lane * 8;

    f32x4 acc[16] = {};
    float4 wA[4], wB[4], wC[4], wD[4];
    bf16x8 aTA[8], aTB[8];

    // prologue: stage ss 0 (serial-ish, once)
    S_CHK(wA, 0, 0) S_CHK(wB, 1, 0) S_CHK(wC, 2, 0) S_CHK(wD, 3, 0)
    W_CHK(wA, 0)    W_CHK(wB, 1)    W_CHK(wC, 2)    W_CHK(wD, 3)
    S_CHK(wA, 4, 0) S_CHK(wB, 5, 0) S_CHK(wC, 6, 0) S_CHK(wD, 7, 0)
    W_CHK(wA, 4)    W_CHK(wB, 5)    W_CHK(wC, 6)    W_CHK(wD, 7)

    for (int sl = 0; sl < SSN; ++sl) {
        const bool more = (sl + 1 < SSN);
        // issue first half of next ss's W loads; they fly during compute
        if (more) { S_CHK(wA, 0, sl+1) S_CHK(wB, 1, sl+1)
                    S_CHK(wC, 2, sl+1) S_CHK(wD, 3, sl+1) }

        // compute ss sl from private LDS; A ping-pong (static names)
        LOAD_A(aTA, sl, 0)
#pragma unroll
        for (int kp = 0; kp < 4; ++kp) {
            LOAD_A(aTB, sl, 2*kp + 1)
            CALC(aTA, 2*kp)
            if (kp < 3) { LOAD_A(aTA, sl, 2*kp + 2) }
            CALC(aTB, 2*kp + 1)
        }

        // publish next ss into private LDS (DS ops in-order per wave; the
        // ds_reads above precede these writes in program order)
        if (more) {
            W_CHK(wA, 0) S_CHK(wA, 4, sl+1)
            W_CHK(wB, 1) S_CHK(wB, 5, sl+1)
            W_CHK(wC, 2) S_CHK(wC, 6, sl+1)
            W_CHK(wD, 3) S_CHK(wD, 7, sl+1)
            W_CHK(wA, 4) W_CHK(wB, 5) W_CHK(wC, 6) W_CHK(wD, 7)
        }
    }

    // D layout: col = lane&15 (m), row = (lane>>4)*4 + reg (b)   [m89/m91]
    float* pz = partial + (size_t)kz * (B_ * M_);
#pragma unroll
    for (int bt = 0; bt < 8; ++bt) {
#pragma unroll
        for (int mi = 0; mi < 2; ++mi) {
            const int m = mt32 * 32 + mi * 16 + r16;
#pragma unroll
            for (int r = 0; r < 4; ++r) {
                const int b = bt * 16 + kg * 4 + r;
                pz[(size_t)b * M_ + m] = acc[bt*2 + mi][r];
            }
        }
    }
}

// ---------------- post: reduce_k | mlp_gemm (block-partitioned) -------------
__global__ __launch_bounds__(256) void post(const float* __restrict__ pp,
                                            const float* __restrict__ EP,
                                            const float* __restrict__ Wm,
                                            float* __restrict__ out) {
    const int bid = blockIdx.x;
    if (bid < 2304) {
        int t = bid * 256 + threadIdx.x;
        int i = t % (B_ * M_);
        int zc = t / (B_ * M_);
        float s = 0.f;
#pragma unroll
        for (int z = zc * (KSPLIT / ZC); z < (zc + 1) * (KSPLIT / ZC); ++z)
            s += pp[(size_t)z * (B_ * M_) + i];
        atomicAdd(out + i, 0.1f * s);
    } else {
        const int wid   = ((bid - 2304) * 256 + threadIdx.x) >> 6;  // 0..383
        const int lane  = threadIdx.x & 63;
        const int bt    = wid & 7;
        const int mt    = wid >> 3;
        const int row16 = lane & 15;
        const int kgrp  = lane >> 4;
        const float* Arow = EP + (size_t)(bt*16 + row16) * (2*E_);
        const float* Brow = Wm + (size_t)(mt*16 + row16) * (2*E_);
        f32x4 acc = {};
        for (int k0 = 0; k0 < 2*E_; k0 += 32) {
            bf16x8 af = cvt8(Arow + k0 + kgrp*8);
            bf16x8 bv = cvt8(Brow + k0 + kgrp*8);
            acc = __builtin_amdgcn_mfma_f32_16x16x32_bf16(af, bv, acc, 0, 0, 0);
        }
        const int m = mt*16 + row16;
#pragma unroll
        for (int r = 0; r < 4; ++r) {
            const int b = bt*16 + kgrp*4 + r;
            atomicAdd(out + b * M_ + m, 0.9f * acc[r]);
        }
    }
}

extern "C" void kernel_launch(void* const* d_in, const int* in_sizes, int n_in,
                              void* d_out, int out_size, void* d_ws, size_t ws_size,
                              hipStream_t stream) {
    const float* se    = (const float*)d_in[0];
    const int*   be    = (const int*)  d_in[1];
    const float* mlp_w = (const float*)d_in[2];
    const float* mlp_b = (const float*)d_in[3];
    const float* fk_w  = (const float*)d_in[4];
    const float* fk_b  = (const float*)d_in[5];
    float* out = (float*)d_out;
    float* ep  = (float*)d_ws;                  // event_pair [128][1536] f32
    float* pp  = ep + (size_t)B_ * 2 * E_;      // partials [KSPLIT][128][768] f32
    __bf16* apk = (__bf16*)(pp + (size_t)KSPLIT * B_ * M_);  // packed A bf16

    const int be_stride = (in_sizes[1] == B_ * 4 * 2) ? 2 : 1;

    prep<<<3584, 256, 0, stream>>>(mlp_b, fk_b, se, be, be_stride, out, ep, apk);
    fk_gemm<<<12 * KSPLIT, 128, 0, stream>>>(apk, fk_w, pp);
    post<<<2400, 256, 0, stream>>>(pp, ep, mlp_w, out);
}